// Round 4
// baseline (584.265 us; speedup 1.0000x reference)
//
#include <hip/hip_runtime.h>

typedef unsigned short ushort_t;
typedef __attribute__((ext_vector_type(8))) unsigned short ushort8;
typedef __attribute__((ext_vector_type(8))) short bf16x8;
typedef __attribute__((ext_vector_type(4))) float f32x4;

#define BB 64
#define II 512
#define DD 128
#define NN 32
#define OO 64

__device__ inline ushort_t f2bf(float f) {
  unsigned int u = __float_as_uint(f);
  u += 0x7FFF + ((u >> 16) & 1);   // RNE
  return (ushort_t)(u >> 16);
}
__device__ inline float bf2f(ushort_t h) {
  return __uint_as_float(((unsigned int)h) << 16);
}

// load 8 contiguous u-elements as fp32
__device__ inline void load8u(const float* p, float* a) {
  f32x4 v0 = *(const f32x4*)p;
  f32x4 v1 = *(const f32x4*)(p + 4);
  a[0]=v0[0]; a[1]=v0[1]; a[2]=v0[2]; a[3]=v0[3];
  a[4]=v1[0]; a[5]=v1[1]; a[6]=v1[2]; a[7]=v1[3];
}
__device__ inline void load8u(const ushort_t* p, float* a) {
  ushort8 v = *(const ushort8*)p;
  #pragma unroll
  for (int e = 0; e < 8; ++e) a[e] = bf2f(v[e]);
}

// ---------------------------------------------------------------------------
// K1: u[b,n,i,o] = sum_d x[b,i,d] * W[n,i,o,d], fp32-accurate via split-bf16:
// u = xh*Wh + xl*Wh + xh*Wl (3 MFMAs). WG = (i, n-block of 8).
// (validated rounds 2-3)
// ---------------------------------------------------------------------------
template<typename UT>
__global__ __launch_bounds__(256) void k_compute_u(
    const float* __restrict__ x, const float* __restrict__ W,
    UT* __restrict__ u)
{
  __shared__ ushort_t Ah[64*128] __attribute__((aligned(16)));
  __shared__ ushort_t Al[64*128] __attribute__((aligned(16)));
  __shared__ ushort_t Bh[64*128] __attribute__((aligned(16)));
  __shared__ ushort_t Bl[64*128] __attribute__((aligned(16)));
  __shared__ float    Cs[64*64]  __attribute__((aligned(16)));
  const int tid  = threadIdx.x;
  const int i    = blockIdx.x;
  const int n0   = blockIdx.y * 8;
  const int w    = tid >> 6;
  const int lane = tid & 63;

  // stage A = x[:, i, :]  (64 b-rows x 128 d), fp32 -> bf16 hi+lo
  for (int k = 0; k < 4; ++k) {
    int flat = tid + 256*k;      // 1024 chunks of 8 floats
    int row  = flat >> 4;
    int c8   = flat & 15;
    const float* gp = x + ((size_t)row*II + i)*DD + c8*8;
    float4 f0 = *(const float4*)(gp);
    float4 f1 = *(const float4*)(gp + 4);
    float fv[8] = {f0.x,f0.y,f0.z,f0.w,f1.x,f1.y,f1.z,f1.w};
    ushort8 h, l;
    #pragma unroll
    for (int e = 0; e < 8; ++e) {
      ushort_t hh = f2bf(fv[e]); h[e] = hh; l[e] = f2bf(fv[e] - bf2f(hh));
    }
    int off = (row*256 + c8*16) ^ ((row & 7) << 4);
    *(ushort8*)((char*)Ah + off) = h;
    *(ushort8*)((char*)Al + off) = l;
  }

  for (int j = 0; j < 8; ++j) {
    int n = n0 + j;
    __syncthreads();  // A staged (j==0); prev iter's Cs->u store done (j>0)

    // stage B = W[n, i, :, :]  (64 o-rows x 128 d), hi+lo
    const float* wbase = W + (((size_t)n*II + i)*OO)*DD;
    for (int k = 0; k < 4; ++k) {
      int flat = tid + 256*k;
      int row  = flat >> 4;
      int c8   = flat & 15;
      const float* gp = wbase + row*DD + c8*8;
      float4 f0 = *(const float4*)(gp);
      float4 f1 = *(const float4*)(gp + 4);
      float fv[8] = {f0.x,f0.y,f0.z,f0.w,f1.x,f1.y,f1.z,f1.w};
      ushort8 h, l;
      #pragma unroll
      for (int e = 0; e < 8; ++e) {
        ushort_t hh = f2bf(fv[e]); h[e] = hh; l[e] = f2bf(fv[e] - bf2f(hh));
      }
      int off = (row*256 + c8*16) ^ ((row & 7) << 4);
      *(ushort8*)((char*)Bh + off) = h;
      *(ushort8*)((char*)Bl + off) = l;
    }
    __syncthreads();

    f32x4 zero = {0.f, 0.f, 0.f, 0.f};
    f32x4 acc[4];
    #pragma unroll
    for (int ot = 0; ot < 4; ++ot) acc[ot] = zero;

    #pragma unroll
    for (int kk = 0; kk < 4; ++kk) {
      int ra   = w*16 + (lane & 15);
      int aoff = (ra*256 + kk*64 + ((lane >> 4) << 4)) ^ ((ra & 7) << 4);
      bf16x8 ah = *(bf16x8*)((char*)Ah + aoff);
      bf16x8 al = *(bf16x8*)((char*)Al + aoff);
      #pragma unroll
      for (int ot = 0; ot < 4; ++ot) {
        int rb   = ot*16 + (lane & 15);
        int boff = (rb*256 + kk*64 + ((lane >> 4) << 4)) ^ ((rb & 7) << 4);
        bf16x8 bh = *(bf16x8*)((char*)Bh + boff);
        bf16x8 bl = *(bf16x8*)((char*)Bl + boff);
        acc[ot] = __builtin_amdgcn_mfma_f32_16x16x32_bf16(ah, bh, acc[ot], 0, 0, 0);
        acc[ot] = __builtin_amdgcn_mfma_f32_16x16x32_bf16(al, bh, acc[ot], 0, 0, 0);
        acc[ot] = __builtin_amdgcn_mfma_f32_16x16x32_bf16(ah, bl, acc[ot], 0, 0, 0);
      }
    }

    // D lane map: col = lane&15, row = (lane>>4)*4 + r  (m89-verified)
    #pragma unroll
    for (int ot = 0; ot < 4; ++ot)
      #pragma unroll
      for (int r = 0; r < 4; ++r) {
        int row = w*16 + ((lane >> 4) << 2) + r;
        int col = ot*16 + (lane & 15);
        Cs[row*64 + col] = acc[ot][r];
      }
    __syncthreads();

    // coalesced store Cs -> u[b, n, i, :]
    for (int k = 0; k < 2; ++k) {
      int flat = tid + 256*k;   // 512 chunks of 8
      int row  = flat >> 3;     // b
      int c8   = flat & 7;
      const float* sp = Cs + row*64 + c8*8;
      UT* dst = u + (((size_t)row*NN + n)*II + i)*OO + c8*8;
      if constexpr (sizeof(UT) == 4) {
        *(f32x4*)dst       = *(const f32x4*)sp;
        *(f32x4*)(dst + 4) = *(const f32x4*)(sp + 4);
      } else {
        ushort8 v;
        #pragma unroll
        for (int e = 0; e < 8; ++e) v[e] = f2bf(sp[e]);
        *(ushort8*)dst = v;
      }
    }
  }
}

// ---------------------------------------------------------------------------
// K2: out0[b,n,o] = (1/32) * sum_i u[b,n,i,o]   (round 0: c uniform)
// (validated round 3)
// ---------------------------------------------------------------------------
template<typename UT>
__global__ __launch_bounds__(256) void k_round0(
    const UT* __restrict__ u, float* __restrict__ out0)
{
  __shared__ float sPart[32*65];
  const int tid = threadIdx.x;
  const int bn  = blockIdx.x;          // b*32+n
  const int ip  = tid >> 3;
  const int o8  = tid & 7;
  const UT* base = u + (size_t)bn * (II*OO);
  float a[8];
  #pragma unroll
  for (int e = 0; e < 8; ++e) a[e] = 0.f;
  for (int i = ip; i < II; i += 32) {
    float t[8];
    load8u(base + (size_t)i*OO + o8*8, t);
    #pragma unroll
    for (int e = 0; e < 8; ++e) a[e] += t[e];
  }
  #pragma unroll
  for (int e = 0; e < 8; ++e) sPart[ip*65 + o8*8 + e] = a[e];
  for (int step = 16; step >= 1; step >>= 1) {
    __syncthreads();
    if (ip < step) {
      #pragma unroll
      for (int e = 0; e < 8; ++e)
        sPart[ip*65 + o8*8 + e] += sPart[(ip+step)*65 + o8*8 + e];
    }
  }
  __syncthreads();
  if (tid < 64) out0[(size_t)bn*OO + tid] = sPart[tid] * (1.f/32.f);
}

// ---------------------------------------------------------------------------
// K3: fused routing round (no atomics):
//  per block (ic, b), 4 sub-rounds of 8 i:
//   phase1: thread (n,q) -> full logit dot for (n, i0+q) -> sL[q][n]
//   softmax: thread (n,q) redundantly reduces column sL[q][:] -> sC[n][q]
//   phase2: a8 += c * u  (re-reads tile; L2/L3-hot)
//  stores partial sums -> part[ic][b][n][o]   (plain stores, deterministic)
// ---------------------------------------------------------------------------
template<typename UT>
__global__ __launch_bounds__(256) void k_round_fused(
    const UT* __restrict__ u, const float* __restrict__ out_prev,
    float* __restrict__ part)
{
  __shared__ float sOut[NN*OO];     // 8 KB
  __shared__ float sL[8][33];       // logits [ii][n], padded
  __shared__ float sC[NN][9];       // softmax coef [n][ii], padded
  const int tid = threadIdx.x;
  const int ic  = blockIdx.x;       // i-chunk, 0..15
  const int b   = blockIdx.y;
  const int n   = tid >> 3;
  const int q   = tid & 7;

  for (int k = 0; k < 8; ++k) {
    int flat = tid + 256*k;
    sOut[flat] = out_prev[(size_t)b*NN*OO + flat];
  }
  float a8[8];
  #pragma unroll
  for (int e = 0; e < 8; ++e) a8[e] = 0.f;
  __syncthreads();

  for (int sub = 0; sub < 4; ++sub) {
    const int i0 = ic*32 + sub*8;
    // phase 1: full 64-o dot for (n, i = i0+q), fixed order
    {
      const UT* up = u + (((size_t)b*NN + n)*II + i0 + q)*OO;
      float acc = 0.f;
      #pragma unroll
      for (int c8 = 0; c8 < 8; ++c8) {
        float t[8];
        load8u(up + c8*8, t);
        #pragma unroll
        for (int e = 0; e < 8; ++e) acc += t[e] * sOut[n*OO + c8*8 + e];
      }
      sL[q][n] = acc;
    }
    __syncthreads();
    // softmax over n, redundantly per thread (identical order -> deterministic)
    {
      float m = -1e30f;
      #pragma unroll
      for (int n2 = 0; n2 < NN; ++n2) m = fmaxf(m, sL[q][n2]);
      float s = 0.f;
      #pragma unroll
      for (int n2 = 0; n2 < NN; ++n2) s += __expf(sL[q][n2] - m);
      sC[n][q] = __expf(sL[q][n] - m) / s;
    }
    __syncthreads();
    // phase 2: accumulate c * u over the 8 i's (cache-hot re-read)
    #pragma unroll
    for (int ii = 0; ii < 8; ++ii) {
      float cv = sC[n][ii];
      float t[8];
      load8u(u + (((size_t)b*NN + n)*II + i0 + ii)*OO + q*8, t);
      #pragma unroll
      for (int e = 0; e < 8; ++e) a8[e] += cv * t[e];
    }
    // no barrier needed here: next phase1 writes sL (disjoint from sC);
    // the barrier after phase1 orders this phase2's sC reads before the
    // next softmax's sC writes.
  }
  float* dst = part + (((size_t)ic*BB + b)*NN + n)*OO + q*8;
  #pragma unroll
  for (int e = 0; e < 8; ++e) dst[e] = a8[e];
}

// ---------------------------------------------------------------------------
// K3b: out_next[j] = sum_{k<16} part[k][j], fixed order. j in [0, B*N*O)
// ---------------------------------------------------------------------------
__global__ __launch_bounds__(256) void k_reduce_part(
    const float* __restrict__ part, float* __restrict__ out_next)
{
  const int j = blockIdx.x*256 + threadIdx.x;   // grid = 512 blocks
  const size_t O = (size_t)BB*NN*OO;
  float s = 0.f;
  #pragma unroll
  for (int k = 0; k < 16; ++k) s += part[(size_t)k*O + j];
  out_next[j] = s;
}

// ---------------------------------------------------------------------------
// K4: lengths[b,n] = sqrt(sum_o out2^2)
// ---------------------------------------------------------------------------
__global__ __launch_bounds__(256) void k_len(
    const float* __restrict__ out2, float* __restrict__ dout)
{
  int t = blockIdx.x*blockDim.x + threadIdx.x;
  if (t < BB*NN) {
    const float* p = out2 + (size_t)t*OO;
    float s = 0.f;
    #pragma unroll
    for (int o = 0; o < OO; ++o) { float f = p[o]; s += f*f; }
    dout[t] = sqrtf(s);
  }
}

template<typename UT>
static void run_pipeline(const float* x, const float* W, UT* u,
                         float* out0, float* out1, float* out2, float* part,
                         float* dout, hipStream_t stream)
{
  k_compute_u<UT>  <<<dim3(II, 4),  dim3(256), 0, stream>>>(x, W, u);
  k_round0<UT>     <<<dim3(BB*NN),  dim3(256), 0, stream>>>(u, out0);
  k_round_fused<UT><<<dim3(16, BB), dim3(256), 0, stream>>>(u, out0, part);
  k_reduce_part    <<<dim3(512),    dim3(256), 0, stream>>>(part, out1);
  k_round_fused<UT><<<dim3(16, BB), dim3(256), 0, stream>>>(u, out1, part);
  k_reduce_part    <<<dim3(512),    dim3(256), 0, stream>>>(part, out2);
  hipLaunchKernelGGL(k_len, dim3(8), dim3(256), 0, stream, out2, dout);
}

extern "C" void kernel_launch(void* const* d_in, const int* in_sizes, int n_in,
                              void* d_out, int out_size, void* d_ws, size_t ws_size,
                              hipStream_t stream)
{
  const float* x = (const float*)d_in[0];
  const float* W = (const float*)d_in[1];
  float* dout = (float*)d_out;

  const size_t U = (size_t)BB*NN*II*OO;   // 67,108,864 elements
  const size_t O = (size_t)BB*NN*OO;      // 131,072

  const size_t need_f32 = U*4 + (3*O + 16*O)*4;   // ~278 MiB
  if (ws_size >= need_f32) {
    float* u    = (float*)d_ws;
    float* out0 = u + U;
    float* out1 = out0 + O;
    float* out2 = out1 + O;
    float* part = out2 + O;
    run_pipeline<float>(x, W, u, out0, out1, out2, part, dout, stream);
  } else {
    ushort_t* u = (ushort_t*)d_ws;
    float* out0 = (float*)((char*)d_ws + U*2);
    float* out1 = out0 + O;
    float* out2 = out1 + O;
    float* part = out2 + O;
    run_pipeline<ushort_t>(x, W, u, out0, out1, out2, part, dout, stream);
  }
}

// Round 5
// 315.523 us; speedup vs baseline: 1.8517x; 1.8517x over previous
//
#include <hip/hip_runtime.h>

typedef unsigned short ushort_t;
typedef __attribute__((ext_vector_type(8))) unsigned short ushort8;
typedef __attribute__((ext_vector_type(8))) short bf16x8;
typedef __attribute__((ext_vector_type(4))) float f32x4;

#define BB 64
#define II 512
#define DD 128
#define NN 32
#define OO 64

__device__ inline ushort_t f2bf(float f) {
  unsigned int u = __float_as_uint(f);
  u += 0x7FFF + ((u >> 16) & 1);   // RNE
  return (ushort_t)(u >> 16);
}
__device__ inline float bf2f(ushort_t h) {
  return __uint_as_float(((unsigned int)h) << 16);
}

// load 8 contiguous u-elements as fp32
__device__ inline void load8u(const float* p, float* a) {
  f32x4 v0 = *(const f32x4*)p;
  f32x4 v1 = *(const f32x4*)(p + 4);
  a[0]=v0[0]; a[1]=v0[1]; a[2]=v0[2]; a[3]=v0[3];
  a[4]=v1[0]; a[5]=v1[1]; a[6]=v1[2]; a[7]=v1[3];
}
__device__ inline void load8u(const ushort_t* p, float* a) {
  ushort8 v = *(const ushort8*)p;
  #pragma unroll
  for (int e = 0; e < 8; ++e) a[e] = bf2f(v[e]);
}

// ---------------------------------------------------------------------------
// K1: u[b,n,i,o] = sum_d x[b,i,d] * W[n,i,o,d], fp32-accurate via split-bf16:
// u = xh*Wh + xl*Wh + xh*Wl (3 MFMAs). WG = (i, n-block of 8).
// (validated rounds 2-4; at its traffic roofline ~6.3 TB/s)
// ---------------------------------------------------------------------------
template<typename UT>
__global__ __launch_bounds__(256) void k_compute_u(
    const float* __restrict__ x, const float* __restrict__ W,
    UT* __restrict__ u)
{
  __shared__ ushort_t Ah[64*128] __attribute__((aligned(16)));
  __shared__ ushort_t Al[64*128] __attribute__((aligned(16)));
  __shared__ ushort_t Bh[64*128] __attribute__((aligned(16)));
  __shared__ ushort_t Bl[64*128] __attribute__((aligned(16)));
  __shared__ float    Cs[64*64]  __attribute__((aligned(16)));
  const int tid  = threadIdx.x;
  const int i    = blockIdx.x;
  const int n0   = blockIdx.y * 8;
  const int w    = tid >> 6;
  const int lane = tid & 63;

  for (int k = 0; k < 4; ++k) {
    int flat = tid + 256*k;      // 1024 chunks of 8 floats
    int row  = flat >> 4;
    int c8   = flat & 15;
    const float* gp = x + ((size_t)row*II + i)*DD + c8*8;
    float4 f0 = *(const float4*)(gp);
    float4 f1 = *(const float4*)(gp + 4);
    float fv[8] = {f0.x,f0.y,f0.z,f0.w,f1.x,f1.y,f1.z,f1.w};
    ushort8 h, l;
    #pragma unroll
    for (int e = 0; e < 8; ++e) {
      ushort_t hh = f2bf(fv[e]); h[e] = hh; l[e] = f2bf(fv[e] - bf2f(hh));
    }
    int off = (row*256 + c8*16) ^ ((row & 7) << 4);
    *(ushort8*)((char*)Ah + off) = h;
    *(ushort8*)((char*)Al + off) = l;
  }

  for (int j = 0; j < 8; ++j) {
    int n = n0 + j;
    __syncthreads();

    const float* wbase = W + (((size_t)n*II + i)*OO)*DD;
    for (int k = 0; k < 4; ++k) {
      int flat = tid + 256*k;
      int row  = flat >> 4;
      int c8   = flat & 15;
      const float* gp = wbase + row*DD + c8*8;
      float4 f0 = *(const float4*)(gp);
      float4 f1 = *(const float4*)(gp + 4);
      float fv[8] = {f0.x,f0.y,f0.z,f0.w,f1.x,f1.y,f1.z,f1.w};
      ushort8 h, l;
      #pragma unroll
      for (int e = 0; e < 8; ++e) {
        ushort_t hh = f2bf(fv[e]); h[e] = hh; l[e] = f2bf(fv[e] - bf2f(hh));
      }
      int off = (row*256 + c8*16) ^ ((row & 7) << 4);
      *(ushort8*)((char*)Bh + off) = h;
      *(ushort8*)((char*)Bl + off) = l;
    }
    __syncthreads();

    f32x4 zero = {0.f, 0.f, 0.f, 0.f};
    f32x4 acc[4];
    #pragma unroll
    for (int ot = 0; ot < 4; ++ot) acc[ot] = zero;

    #pragma unroll
    for (int kk = 0; kk < 4; ++kk) {
      int ra   = w*16 + (lane & 15);
      int aoff = (ra*256 + kk*64 + ((lane >> 4) << 4)) ^ ((ra & 7) << 4);
      bf16x8 ah = *(bf16x8*)((char*)Ah + aoff);
      bf16x8 al = *(bf16x8*)((char*)Al + aoff);
      #pragma unroll
      for (int ot = 0; ot < 4; ++ot) {
        int rb   = ot*16 + (lane & 15);
        int boff = (rb*256 + kk*64 + ((lane >> 4) << 4)) ^ ((rb & 7) << 4);
        bf16x8 bh = *(bf16x8*)((char*)Bh + boff);
        bf16x8 bl = *(bf16x8*)((char*)Bl + boff);
        acc[ot] = __builtin_amdgcn_mfma_f32_16x16x32_bf16(ah, bh, acc[ot], 0, 0, 0);
        acc[ot] = __builtin_amdgcn_mfma_f32_16x16x32_bf16(al, bh, acc[ot], 0, 0, 0);
        acc[ot] = __builtin_amdgcn_mfma_f32_16x16x32_bf16(ah, bl, acc[ot], 0, 0, 0);
      }
    }

    #pragma unroll
    for (int ot = 0; ot < 4; ++ot)
      #pragma unroll
      for (int r = 0; r < 4; ++r) {
        int row = w*16 + ((lane >> 4) << 2) + r;
        int col = ot*16 + (lane & 15);
        Cs[row*64 + col] = acc[ot][r];
      }
    __syncthreads();

    for (int k = 0; k < 2; ++k) {
      int flat = tid + 256*k;
      int row  = flat >> 3;
      int c8   = flat & 7;
      const float* sp = Cs + row*64 + c8*8;
      UT* dst = u + (((size_t)row*NN + n)*II + i)*OO + c8*8;
      if constexpr (sizeof(UT) == 4) {
        *(f32x4*)dst       = *(const f32x4*)sp;
        *(f32x4*)(dst + 4) = *(const f32x4*)(sp + 4);
      } else {
        ushort8 v;
        #pragma unroll
        for (int e = 0; e < 8; ++e) v[e] = f2bf(sp[e]);
        *(ushort8*)dst = v;
      }
    }
  }
}

// ---------------------------------------------------------------------------
// K2: out0[b,n,o] = (1/32) * sum_i u[b,n,i,o]   (validated)
// ---------------------------------------------------------------------------
template<typename UT>
__global__ __launch_bounds__(256) void k_round0(
    const UT* __restrict__ u, float* __restrict__ out0)
{
  __shared__ float sPart[32*65];
  const int tid = threadIdx.x;
  const int bn  = blockIdx.x;
  const int ip  = tid >> 3;
  const int o8  = tid & 7;
  const UT* base = u + (size_t)bn * (II*OO);
  float a[8];
  #pragma unroll
  for (int e = 0; e < 8; ++e) a[e] = 0.f;
  for (int i = ip; i < II; i += 32) {
    float t[8];
    load8u(base + (size_t)i*OO + o8*8, t);
    #pragma unroll
    for (int e = 0; e < 8; ++e) a[e] += t[e];
  }
  #pragma unroll
  for (int e = 0; e < 8; ++e) sPart[ip*65 + o8*8 + e] = a[e];
  for (int step = 16; step >= 1; step >>= 1) {
    __syncthreads();
    if (ip < step) {
      #pragma unroll
      for (int e = 0; e < 8; ++e)
        sPart[ip*65 + o8*8 + e] += sPart[(ip+step)*65 + o8*8 + e];
    }
  }
  __syncthreads();
  if (tid < 64) out0[(size_t)bn*OO + tid] = sPart[tid] * (1.f/32.f);
}

// ---------------------------------------------------------------------------
// K3: register-fused routing round — ONE pass over u per round.
// Block = (ichunk of 64 i, b). Thread (n,q): per sub of 16 i, load
// r[16][8] = u[b,n,i0..i0+15, q*8..q*8+7] into VGPRs; partial dots -> LDS
// reduce -> redundant fixed-order softmax over n -> phase2 from REGISTERS.
// Partials to part[ic][b][n][o]; no atomics; deterministic.
// ---------------------------------------------------------------------------
template<typename UT>
__global__ __launch_bounds__(256, 2) void k_round_reg(
    const UT* __restrict__ u, const float* __restrict__ out_prev,
    float* __restrict__ part)
{
  __shared__ float sOut[NN*OO];        // 8 KB
  __shared__ float sP[NN][16][9];      // 18 KB (pad 9 kills 8-way conflicts)
  __shared__ float sLog[16][NN+1];
  __shared__ float sC[16][NN+1];
  const int tid = threadIdx.x;
  const int ic  = blockIdx.x;          // 0..7
  const int b   = blockIdx.y;
  const int n   = tid >> 3;
  const int q   = tid & 7;

  for (int k = 0; k < 8; ++k) {
    int flat = tid + 256*k;
    sOut[flat] = out_prev[(size_t)b*NN*OO + flat];
  }
  float a8[8];
  #pragma unroll
  for (int e = 0; e < 8; ++e) a8[e] = 0.f;
  __syncthreads();

  const UT* ubase = u + ((size_t)b*NN + n)*II*OO;
  for (int s = 0; s < 4; ++s) {
    const int i0 = ic*64 + s*16;
    float r[16][8];
    // phase 1: load 16 i-rows' o-chunk into regs + partial logit dots
    #pragma unroll
    for (int ii = 0; ii < 16; ++ii) {
      load8u(ubase + (size_t)(i0+ii)*OO + q*8, r[ii]);
      float acc = 0.f;
      #pragma unroll
      for (int e = 0; e < 8; ++e) acc += r[ii][e] * sOut[n*OO + q*8 + e];
      sP[n][ii][q] = acc;
    }
    __syncthreads();
    // logits: thread handles ii = q and q+8
    #pragma unroll
    for (int h = 0; h < 2; ++h) {
      int ii = q + h*8;
      float sum = 0.f;
      #pragma unroll
      for (int q2 = 0; q2 < 8; ++q2) sum += sP[n][ii][q2];
      sLog[ii][n] = sum;
    }
    __syncthreads();
    // softmax over n (redundant, fixed order -> deterministic)
    #pragma unroll
    for (int h = 0; h < 2; ++h) {
      int ii = q + h*8;
      float m = -1e30f;
      #pragma unroll
      for (int n2 = 0; n2 < NN; ++n2) m = fmaxf(m, sLog[ii][n2]);
      float ss = 0.f;
      #pragma unroll
      for (int n2 = 0; n2 < NN; ++n2) ss += __expf(sLog[ii][n2] - m);
      sC[ii][n] = __expf(sLog[ii][n] - m) / ss;
    }
    __syncthreads();
    // phase 2: entirely from registers
    #pragma unroll
    for (int ii = 0; ii < 16; ++ii) {
      float cv = sC[ii][n];
      #pragma unroll
      for (int e = 0; e < 8; ++e) a8[e] += cv * r[ii][e];
    }
    // next s's sP writes are ordered by the barrier after them; sC reads
    // here complete before any thread reaches the next softmax (bar-protected)
  }
  float* dst = part + (((size_t)ic*BB + b)*NN + n)*OO + q*8;
  #pragma unroll
  for (int e = 0; e < 8; ++e) dst[e] = a8[e];
}

// ---------------------------------------------------------------------------
// K3b: out_next[j] = sum_{k<8} part[k][j], fixed order.
// ---------------------------------------------------------------------------
__global__ __launch_bounds__(256) void k_reduce_part(
    const float* __restrict__ part, float* __restrict__ out_next)
{
  const int j = blockIdx.x*256 + threadIdx.x;   // grid = 512
  const size_t O = (size_t)BB*NN*OO;
  float s = 0.f;
  #pragma unroll
  for (int k = 0; k < 8; ++k) s += part[(size_t)k*O + j];
  out_next[j] = s;
}

// ---------------------------------------------------------------------------
// K4: lengths[b,n] = sqrt(sum_o out2^2)
// ---------------------------------------------------------------------------
__global__ __launch_bounds__(256) void k_len(
    const float* __restrict__ out2, float* __restrict__ dout)
{
  int t = blockIdx.x*blockDim.x + threadIdx.x;
  if (t < BB*NN) {
    const float* p = out2 + (size_t)t*OO;
    float s = 0.f;
    #pragma unroll
    for (int o = 0; o < OO; ++o) { float f = p[o]; s += f*f; }
    dout[t] = sqrtf(s);
  }
}

template<typename UT>
static void run_pipeline(const float* x, const float* W, UT* u,
                         float* out0, float* out1, float* out2, float* part,
                         float* dout, hipStream_t stream)
{
  k_compute_u<UT><<<dim3(II, 4),  dim3(256), 0, stream>>>(x, W, u);
  k_round0<UT>   <<<dim3(BB*NN),  dim3(256), 0, stream>>>(u, out0);
  k_round_reg<UT><<<dim3(8, BB),  dim3(256), 0, stream>>>(u, out0, part);
  k_reduce_part  <<<dim3(512),    dim3(256), 0, stream>>>(part, out1);
  k_round_reg<UT><<<dim3(8, BB),  dim3(256), 0, stream>>>(u, out1, part);
  k_reduce_part  <<<dim3(512),    dim3(256), 0, stream>>>(part, out2);
  hipLaunchKernelGGL(k_len, dim3(8), dim3(256), 0, stream, out2, dout);
}

extern "C" void kernel_launch(void* const* d_in, const int* in_sizes, int n_in,
                              void* d_out, int out_size, void* d_ws, size_t ws_size,
                              hipStream_t stream)
{
  const float* x = (const float*)d_in[0];
  const float* W = (const float*)d_in[1];
  float* dout = (float*)d_out;

  const size_t U = (size_t)BB*NN*II*OO;   // 67,108,864 elements
  const size_t O = (size_t)BB*NN*OO;      // 131,072

  const size_t need_f32 = U*4 + (3*O + 8*O)*4;
  if (ws_size >= need_f32) {
    float* u    = (float*)d_ws;
    float* out0 = u + U;
    float* out1 = out0 + O;
    float* out2 = out1 + O;
    float* part = out2 + O;
    run_pipeline<float>(x, W, u, out0, out1, out2, part, dout, stream);
  } else {
    ushort_t* u = (ushort_t*)d_ws;
    float* out0 = (float*)((char*)d_ws + U*2);
    float* out1 = out0 + O;
    float* out2 = out1 + O;
    float* part = out2 + O;
    run_pipeline<ushort_t>(x, W, u, out0, out1, out2, part, dout, stream);
  }
}

// Round 6
// 218.019 us; speedup vs baseline: 2.6799x; 1.4472x over previous
//
#include <hip/hip_runtime.h>

typedef unsigned short ushort_t;
typedef _Float16 half_t;
typedef __attribute__((ext_vector_type(8))) unsigned short ushort8;
typedef __attribute__((ext_vector_type(8))) _Float16 half8;
typedef __attribute__((ext_vector_type(8))) short bf16x8;
typedef __attribute__((ext_vector_type(4))) float f32x4;

#define BB 64
#define II 512
#define DD 128
#define NN 32
#define OO 64

__device__ inline ushort_t f2bf(float f) {
  unsigned int u = __float_as_uint(f);
  u += 0x7FFF + ((u >> 16) & 1);   // RNE
  return (ushort_t)(u >> 16);
}
__device__ inline float bf2f(ushort_t h) {
  return __uint_as_float(((unsigned int)h) << 16);
}

// load 8 contiguous u-elements (fp16) as fp32
__device__ inline void load8u(const half_t* p, float* a) {
  half8 v = *(const half8*)p;
  #pragma unroll
  for (int e = 0; e < 8; ++e) a[e] = (float)v[e];
}

// ---------------------------------------------------------------------------
// K1: u[b,n,i,o] = sum_d x[b,i,d] * W[n,i,o,d], fp32-accurate via split-bf16:
// u = xh*Wh + xl*Wh + xh*Wl (3 MFMAs). WG = (i, n-block of 8).
// u stored as fp16 (|u|max ~9 << 65504; rel err 2^-11 -> negligible).
// (MFMA core validated rounds 2-5)
// ---------------------------------------------------------------------------
__global__ __launch_bounds__(256) void k_compute_u(
    const float* __restrict__ x, const float* __restrict__ W,
    half_t* __restrict__ u)
{
  __shared__ ushort_t Ah[64*128] __attribute__((aligned(16)));
  __shared__ ushort_t Al[64*128] __attribute__((aligned(16)));
  __shared__ ushort_t Bh[64*128] __attribute__((aligned(16)));
  __shared__ ushort_t Bl[64*128] __attribute__((aligned(16)));
  __shared__ float    Cs[64*64]  __attribute__((aligned(16)));
  const int tid  = threadIdx.x;
  const int i    = blockIdx.x;
  const int n0   = blockIdx.y * 8;
  const int w    = tid >> 6;
  const int lane = tid & 63;

  // stage A = x[:, i, :]  (64 b-rows x 128 d), fp32 -> bf16 hi+lo
  for (int k = 0; k < 4; ++k) {
    int flat = tid + 256*k;      // 1024 chunks of 8 floats
    int row  = flat >> 4;
    int c8   = flat & 15;
    const float* gp = x + ((size_t)row*II + i)*DD + c8*8;
    float4 f0 = *(const float4*)(gp);
    float4 f1 = *(const float4*)(gp + 4);
    float fv[8] = {f0.x,f0.y,f0.z,f0.w,f1.x,f1.y,f1.z,f1.w};
    ushort8 h, l;
    #pragma unroll
    for (int e = 0; e < 8; ++e) {
      ushort_t hh = f2bf(fv[e]); h[e] = hh; l[e] = f2bf(fv[e] - bf2f(hh));
    }
    int off = (row*256 + c8*16) ^ ((row & 7) << 4);
    *(ushort8*)((char*)Ah + off) = h;
    *(ushort8*)((char*)Al + off) = l;
  }

  for (int j = 0; j < 8; ++j) {
    int n = n0 + j;
    __syncthreads();  // A staged (j==0); prev iter's Cs->u store done (j>0)

    // stage B = W[n, i, :, :]  (64 o-rows x 128 d), hi+lo
    const float* wbase = W + (((size_t)n*II + i)*OO)*DD;
    for (int k = 0; k < 4; ++k) {
      int flat = tid + 256*k;
      int row  = flat >> 4;
      int c8   = flat & 15;
      const float* gp = wbase + row*DD + c8*8;
      float4 f0 = *(const float4*)(gp);
      float4 f1 = *(const float4*)(gp + 4);
      float fv[8] = {f0.x,f0.y,f0.z,f0.w,f1.x,f1.y,f1.z,f1.w};
      ushort8 h, l;
      #pragma unroll
      for (int e = 0; e < 8; ++e) {
        ushort_t hh = f2bf(fv[e]); h[e] = hh; l[e] = f2bf(fv[e] - bf2f(hh));
      }
      int off = (row*256 + c8*16) ^ ((row & 7) << 4);
      *(ushort8*)((char*)Bh + off) = h;
      *(ushort8*)((char*)Bl + off) = l;
    }
    __syncthreads();

    f32x4 zero = {0.f, 0.f, 0.f, 0.f};
    f32x4 acc[4];
    #pragma unroll
    for (int ot = 0; ot < 4; ++ot) acc[ot] = zero;

    #pragma unroll
    for (int kk = 0; kk < 4; ++kk) {
      int ra   = w*16 + (lane & 15);
      int aoff = (ra*256 + kk*64 + ((lane >> 4) << 4)) ^ ((ra & 7) << 4);
      bf16x8 ah = *(bf16x8*)((char*)Ah + aoff);
      bf16x8 al = *(bf16x8*)((char*)Al + aoff);
      #pragma unroll
      for (int ot = 0; ot < 4; ++ot) {
        int rb   = ot*16 + (lane & 15);
        int boff = (rb*256 + kk*64 + ((lane >> 4) << 4)) ^ ((rb & 7) << 4);
        bf16x8 bh = *(bf16x8*)((char*)Bh + boff);
        bf16x8 bl = *(bf16x8*)((char*)Bl + boff);
        acc[ot] = __builtin_amdgcn_mfma_f32_16x16x32_bf16(ah, bh, acc[ot], 0, 0, 0);
        acc[ot] = __builtin_amdgcn_mfma_f32_16x16x32_bf16(al, bh, acc[ot], 0, 0, 0);
        acc[ot] = __builtin_amdgcn_mfma_f32_16x16x32_bf16(ah, bl, acc[ot], 0, 0, 0);
      }
    }

    // D lane map: col = lane&15, row = (lane>>4)*4 + r  (m89-verified)
    #pragma unroll
    for (int ot = 0; ot < 4; ++ot)
      #pragma unroll
      for (int r = 0; r < 4; ++r) {
        int row = w*16 + ((lane >> 4) << 2) + r;
        int col = ot*16 + (lane & 15);
        Cs[row*64 + col] = acc[ot][r];
      }
    __syncthreads();

    // coalesced store Cs -> u[b, n, i, :] as fp16
    for (int k = 0; k < 2; ++k) {
      int flat = tid + 256*k;   // 512 chunks of 8
      int row  = flat >> 3;     // b
      int c8   = flat & 7;
      const float* sp = Cs + row*64 + c8*8;
      half8 v;
      #pragma unroll
      for (int e = 0; e < 8; ++e) v[e] = (half_t)sp[e];
      *(half8*)(u + (((size_t)row*NN + n)*II + i)*OO + c8*8) = v;
    }
  }
}

// ---------------------------------------------------------------------------
// K2: out0[b,n,o] = (1/32) * sum_i u[b,n,i,o]   (round 0: c uniform)
// ---------------------------------------------------------------------------
__global__ __launch_bounds__(256) void k_round0(
    const half_t* __restrict__ u, float* __restrict__ out0)
{
  __shared__ float sPart[32*65];
  const int tid = threadIdx.x;
  const int bn  = blockIdx.x;          // b*32+n
  const int ip  = tid >> 3;
  const int o8  = tid & 7;
  const half_t* base = u + (size_t)bn * (II*OO);
  float a[8];
  #pragma unroll
  for (int e = 0; e < 8; ++e) a[e] = 0.f;
  for (int i = ip; i < II; i += 32) {
    float t[8];
    load8u(base + (size_t)i*OO + o8*8, t);
    #pragma unroll
    for (int e = 0; e < 8; ++e) a[e] += t[e];
  }
  #pragma unroll
  for (int e = 0; e < 8; ++e) sPart[ip*65 + o8*8 + e] = a[e];
  for (int step = 16; step >= 1; step >>= 1) {
    __syncthreads();
    if (ip < step) {
      #pragma unroll
      for (int e = 0; e < 8; ++e)
        sPart[ip*65 + o8*8 + e] += sPart[(ip+step)*65 + o8*8 + e];
    }
  }
  __syncthreads();
  if (tid < 64) out0[(size_t)bn*OO + tid] = sPart[tid] * (1.f/32.f);
}

// ---------------------------------------------------------------------------
// K3: register-fused routing round — ONE pass over u per round.
// Block = (ichunk of 64 i, b). Thread (n,q): per sub of 16 i, load
// r[16][8] into VGPRs; partial dots -> LDS reduce -> redundant fixed-order
// softmax over n -> phase2 from REGISTERS. No atomics; deterministic.
// (validated round 5)
// ---------------------------------------------------------------------------
__global__ __launch_bounds__(256, 2) void k_round_reg(
    const half_t* __restrict__ u, const float* __restrict__ out_prev,
    float* __restrict__ part)
{
  __shared__ float sOut[NN*OO];        // 8 KB
  __shared__ float sP[NN][16][9];      // 18 KB (pad 9 kills 8-way conflicts)
  __shared__ float sLog[16][NN+1];
  __shared__ float sC[16][NN+1];
  const int tid = threadIdx.x;
  const int ic  = blockIdx.x;          // 0..7
  const int b   = blockIdx.y;
  const int n   = tid >> 3;
  const int q   = tid & 7;

  for (int k = 0; k < 8; ++k) {
    int flat = tid + 256*k;
    sOut[flat] = out_prev[(size_t)b*NN*OO + flat];
  }
  float a8[8];
  #pragma unroll
  for (int e = 0; e < 8; ++e) a8[e] = 0.f;
  __syncthreads();

  const half_t* ubase = u + ((size_t)b*NN + n)*II*OO;
  for (int s = 0; s < 4; ++s) {
    const int i0 = ic*64 + s*16;
    float r[16][8];
    // phase 1: load 16 i-rows' o-chunk into regs + partial logit dots
    #pragma unroll
    for (int ii = 0; ii < 16; ++ii) {
      load8u(ubase + (size_t)(i0+ii)*OO + q*8, r[ii]);
      float acc = 0.f;
      #pragma unroll
      for (int e = 0; e < 8; ++e) acc += r[ii][e] * sOut[n*OO + q*8 + e];
      sP[n][ii][q] = acc;
    }
    __syncthreads();
    // logits: thread handles ii = q and q+8
    #pragma unroll
    for (int h = 0; h < 2; ++h) {
      int ii = q + h*8;
      float sum = 0.f;
      #pragma unroll
      for (int q2 = 0; q2 < 8; ++q2) sum += sP[n][ii][q2];
      sLog[ii][n] = sum;
    }
    __syncthreads();
    // softmax over n (redundant, fixed order -> deterministic)
    #pragma unroll
    for (int h = 0; h < 2; ++h) {
      int ii = q + h*8;
      float m = -1e30f;
      #pragma unroll
      for (int n2 = 0; n2 < NN; ++n2) m = fmaxf(m, sLog[ii][n2]);
      float ss = 0.f;
      #pragma unroll
      for (int n2 = 0; n2 < NN; ++n2) ss += __expf(sLog[ii][n2] - m);
      sC[ii][n] = __expf(sLog[ii][n] - m) / ss;
    }
    __syncthreads();
    // phase 2: entirely from registers
    #pragma unroll
    for (int ii = 0; ii < 16; ++ii) {
      float cv = sC[ii][n];
      #pragma unroll
      for (int e = 0; e < 8; ++e) a8[e] += cv * r[ii][e];
    }
  }
  float* dst = part + (((size_t)ic*BB + b)*NN + n)*OO + q*8;
  #pragma unroll
  for (int e = 0; e < 8; ++e) dst[e] = a8[e];
}

// ---------------------------------------------------------------------------
// K3b: out_next[j] = sum_{k<8} part[k][j], fixed order.
// ---------------------------------------------------------------------------
__global__ __launch_bounds__(256) void k_reduce_part(
    const float* __restrict__ part, float* __restrict__ out_next)
{
  const int j = blockIdx.x*256 + threadIdx.x;   // grid = 512
  const size_t O = (size_t)BB*NN*OO;
  float s = 0.f;
  #pragma unroll
  for (int k = 0; k < 8; ++k) s += part[(size_t)k*O + j];
  out_next[j] = s;
}

// ---------------------------------------------------------------------------
// K4: lengths[b,n] = sqrt(sum_o out2^2)
// ---------------------------------------------------------------------------
__global__ __launch_bounds__(256) void k_len(
    const float* __restrict__ out2, float* __restrict__ dout)
{
  int t = blockIdx.x*blockDim.x + threadIdx.x;
  if (t < BB*NN) {
    const float* p = out2 + (size_t)t*OO;
    float s = 0.f;
    #pragma unroll
    for (int o = 0; o < OO; ++o) { float f = p[o]; s += f*f; }
    dout[t] = sqrtf(s);
  }
}

extern "C" void kernel_launch(void* const* d_in, const int* in_sizes, int n_in,
                              void* d_out, int out_size, void* d_ws, size_t ws_size,
                              hipStream_t stream)
{
  const float* x = (const float*)d_in[0];
  const float* W = (const float*)d_in[1];
  float* dout = (float*)d_out;

  const size_t U = (size_t)BB*NN*II*OO;   // 67,108,864 elements
  const size_t O = (size_t)BB*NN*OO;      // 131,072

  half_t* u   = (half_t*)d_ws;                      // 128 MiB fp16
  float* out0 = (float*)((char*)d_ws + U*2);
  float* out1 = out0 + O;
  float* out2 = out1 + O;
  float* part = out2 + O;                           // 8*O floats = 4 MiB

  k_compute_u  <<<dim3(II, 4),  dim3(256), 0, stream>>>(x, W, u);
  k_round0     <<<dim3(BB*NN),  dim3(256), 0, stream>>>(u, out0);
  k_round_reg  <<<dim3(8, BB),  dim3(256), 0, stream>>>(u, out0, part);
  k_reduce_part<<<dim3(512),    dim3(256), 0, stream>>>(part, out1);
  k_round_reg  <<<dim3(8, BB),  dim3(256), 0, stream>>>(u, out1, part);
  k_reduce_part<<<dim3(512),    dim3(256), 0, stream>>>(part, out2);
  hipLaunchKernelGGL(k_len, dim3(8), dim3(256), 0, stream, out2, dout);
}